// Round 6
// baseline (5158.662 us; speedup 1.0000x reference)
//
#include <hip/hip_runtime.h>
#include <math.h>

namespace {

constexpr int B = 512, T = 96, IN = 64, H = 512, G4 = 2048;
constexpr int FN = 32, KC = 544, NPRED = 24, TM1 = T - 1;
constexpr int BH = B * H;

typedef __attribute__((ext_vector_type(8))) short s8v;    // 8 bf16
typedef __attribute__((ext_vector_type(16))) float f16v;  // 32x32 acc

__device__ __forceinline__ float sigf(float x) { return 1.0f / (1.0f + __expf(-x)); }
__device__ __forceinline__ float tanhfast(float x) {
  x = fminf(fmaxf(x, -15.f), 15.f);
  float e = __expf(2.0f * x);
  return (e - 1.0f) / (e + 1.0f);
}
__device__ __forceinline__ unsigned short bf16_rne(float f) {
  unsigned u = __float_as_uint(f);
  u += 0x7fffu + ((u >> 16) & 1u);
  return (unsigned short)(u >> 16);
}
__device__ __forceinline__ void split8(const float4& x, const float4& y, s8v& hi, s8v& lo) {
  float vs[8] = {x.x, x.y, x.z, x.w, y.x, y.y, y.z, y.w};
#pragma unroll
  for (int j = 0; j < 8; ++j) {
    unsigned ub = __float_as_uint(vs[j]);
    hi[j] = (short)(ub >> 16);
    lo[j] = (short)bf16_rne(vs[j] - __uint_as_float(ub & 0xffff0000u));
  }
}

// ---- Kernel 1: xc = relu(x @ Wh^T + bh) + embed[sid], f32 planes [t][b][h] ----
__global__ __launch_bounds__(256) void k_xc(
    const float* __restrict__ x, const int* __restrict__ sid,
    const float* __restrict__ Wh, const float* __restrict__ bh,
    const float* __restrict__ emb, float* __restrict__ planes) {
  constexpr int RWS = 64;
  int gid = blockIdx.x;
  int half = gid & 1;
  int row0 = (gid >> 1) * RWS;
  int tid = threadIdx.x;
  int h = half * 256 + tid;
  __shared__ float sx[RWS][IN];  // 16 KB
  {
    const float4* xsrc = (const float4*)(x + (size_t)row0 * IN);
    float4* sdst = (float4*)(&sx[0][0]);
    for (int i = tid; i < RWS * IN / 4; i += 256) sdst[i] = xsrc[i];
  }
  float4 w[16];
  const float* wr = Wh + (size_t)h * IN;
#pragma unroll
  for (int j = 0; j < 16; ++j) w[j] = *(const float4*)(wr + j * 4);
  float b0 = bh[h];
  const float* ep = emb + h;
  __syncthreads();
#pragma unroll 2
  for (int r = 0; r < RWS; ++r) {
    float a0 = b0, a1 = 0.f, a2 = 0.f, a3 = 0.f;
#pragma unroll
    for (int j = 0; j < 16; ++j) {
      float4 xv = *(const float4*)(&sx[r][j * 4]);
      a0 = fmaf(xv.x, w[j].x, a0);
      a1 = fmaf(xv.y, w[j].y, a1);
      a2 = fmaf(xv.z, w[j].z, a2);
      a3 = fmaf(xv.w, w[j].w, a3);
    }
    float acc = (a0 + a1) + (a2 + a3);
    int row = row0 + r;
    int bb = row / T, t = row % T;
    float v = fmaxf(acc, 0.f) + ep[(size_t)sid[bb] * H];
    planes[((size_t)t * B + bb) * H + h] = v;
  }
}

// ---- Kernel 2: pre-swizzle weights into frag-linear split-bf16 ----
// frag f = ((layer*16+ng)*64 + kt)*4 + nt ; element o = f*512 + lane*8
// frag content: n-row = nt*512 + ng*32 + (lane&31); k = kt*16 + (lane>>5)*8 + j
__global__ __launch_bounds__(256) void k_wswz(
    const float* __restrict__ Wih, const float* __restrict__ Whh,
    short* __restrict__ WFhi, short* __restrict__ WFlo) {
  int g = blockIdx.x * 256 + threadIdx.x;
  int lane = g & 63;
  int fi = g >> 6;  // 0..8191
  int nt = fi & 3, kt = (fi >> 2) & 63, ng = (fi >> 8) & 15, layer = fi >> 12;
  int row = nt * H + ng * 32 + (lane & 31);
  int kk = kt * 16 + (lane >> 5) * 8;
  const float* src = (kk < H) ? (Wih + ((size_t)layer * G4 + row) * H + kk)
                              : (Whh + ((size_t)layer * G4 + row) * H + (kk - H));
  float4 f0 = *(const float4*)src, f1 = *(const float4*)(src + 4);
  s8v hi, lo;
  split8(f0, f1, hi, lo);
  size_t o = (size_t)fi * 512 + lane * 8;
  *(s8v*)(WFhi + o) = hi;
  *(s8v*)(WFlo + o) = lo;
}

// ---- Kernel 3 (v6): PERSISTENT LSTM, W RESIDENT IN VGPRs ----
// Diagnosis r0-r5: every k_step variant streams the full 16MB split-bf16 W
// from HBM each step (r2 FETCH=17.5MB/dispatch; 21us = 17.5MB/0.83TB/s).
// Kernel-boundary L2 invalidation (the very mechanism giving multi-launch
// its h-coherence) kills W reuse; persistent r4 still thrashed (4MB W/XCD =
// full L2). Fix: W never touches memory again -> 256 VGPRs of W per wave.
// 256 blocks x 512 thr (8 waves, 2/SIMD, 1 block/CU). Block = (layer,ng) x
// 64-row btile; wave = (kqh = K-half, nt = gate): W/wave = 32 kt x {hi,lo}
// frags = 64KB. A (h/x) = normal CACHED loads; cross-XCD visibility per step
// via release/acquire at the grid barrier: syncthreads (stores->L2) ->
// tid0: threadfence_system (buffer_wbl2: L2->IF$) -> system counter add +
// spin -> threadfence_system (buffer_inv: L1/L2 inval) -> syncthreads.
// Stale lines impossible (reader L2 invalidated); W immune (registers).
// c-state in registers. Math identical to r2/r5 (3-product split-bf16).
__global__ __launch_bounds__(512, 1) void k_lstm6(
    float* __restrict__ planes, const short* __restrict__ WFhi,
    const short* __restrict__ WFlo, short* __restrict__ hFhi,
    short* __restrict__ hFlo, const float* __restrict__ bih,
    const float* __restrict__ bhh, unsigned* __restrict__ bar) {
  int gid = blockIdx.x;           // 0..255
  int xcd = gid & 7;
  int u = gid >> 3;               // 0..31
  int combo = xcd * 4 + (u & 3);  // (layer,ng)
  int layer = combo >> 4;
  int ng = combo & 15;
  int btile = u >> 2;             // 0..7
  int b0 = btile * 64;
  int tid = threadIdx.x, lane = tid & 63;
  int wv = tid >> 6;              // 0..7
  int kqh = wv & 1, nt = wv >> 1; // K-half, gate; same-kqh waves pair on a SIMD
  int l31 = lane & 31, lh = lane >> 5;

  __shared__ float comb[2][4][64][32];  // [kqh][nt][row][col] 128 KB

  float bias[4];
#pragma unroll
  for (int q = 0; q < 4; ++q) {
    int r = layer * G4 + q * H + ng * 32 + (tid & 31);
    bias[q] = bih[r] + bhh[r];
  }
  float creg[4] = {0.f, 0.f, 0.f, 0.f};

  // ---- W preload into registers: 64 s8v frags = 256 VGPR ----
  const size_t wstep = 4 * 512;  // shorts per kt
  const size_t wb = (((size_t)(layer * 16 + ng) * 64 + (size_t)kqh * 32) * 4 + nt) * 512 +
                    (size_t)lane * 8;
  s8v wh[32], wl[32];
#pragma unroll
  for (int i = 0; i < 32; ++i) {
    size_t wo = wb + (size_t)i * wstep;
    wh[i] = *(const s8v*)(WFhi + wo);
    wl[i] = *(const s8v*)(WFlo + wo);
  }

  const bool use_x = (layer == 0) && (kqh == 0);
  const int srcA = (layer == 0) ? 0 : ((kqh == 0) ? 0 : 1);
  const size_t astep = (size_t)H * 16;  // shorts per kt in hF

#pragma unroll 1
  for (int tt = 0; tt <= T; ++tt) {
    bool active = layer ? (tt >= 1) : (tt < T);
    int step = layer ? (tt - 1) : tt;
    if (active) {
      int rpar = (step - 1) & 1;  // (-1)&1==1: zeroed initial-state buffer
      const float* xbase = nullptr;
      const short *abhi = nullptr, *ablo = nullptr;
      if (use_x) {
        xbase = planes + (size_t)step * BH + (size_t)(b0 + l31) * H + lh * 8;
      } else {
        int par = (layer == 0) ? rpar : ((kqh == 0) ? (step & 1) : rpar);
        size_t o = ((((size_t)srcA * 2 + par) * 32) * H + (size_t)(b0 + l31)) * 16 + lh * 8;
        abhi = hFhi + o;
        ablo = hFlo + o;
      }

      f16v acc0, acc1;  // rt0 rows 0..31, rt1 rows 32..63
#pragma unroll
      for (int e = 0; e < 16; ++e) acc0[e] = acc1[e] = 0.f;

#pragma unroll
      for (int i = 0; i < 32; ++i) {
        s8v ah0, al0, ah1, al1;
        if (use_x) {
          const float* ap = xbase + i * 16;
          float4 f0 = *(const float4*)ap, f1 = *(const float4*)(ap + 4);
          split8(f0, f1, ah0, al0);
          const float* aq = ap + 32 * H;
          float4 g0 = *(const float4*)aq, g1 = *(const float4*)(aq + 4);
          split8(g0, g1, ah1, al1);
        } else {
          const short* ph_ = abhi + (size_t)i * astep;
          const short* pl_ = ablo + (size_t)i * astep;
          ah0 = *(const s8v*)(ph_);
          al0 = *(const s8v*)(pl_);
          ah1 = *(const s8v*)(ph_ + 512);
          al1 = *(const s8v*)(pl_ + 512);
        }
        acc0 = __builtin_amdgcn_mfma_f32_32x32x16_bf16(ah0, wh[i], acc0, 0, 0, 0);
        acc0 = __builtin_amdgcn_mfma_f32_32x32x16_bf16(ah0, wl[i], acc0, 0, 0, 0);
        acc0 = __builtin_amdgcn_mfma_f32_32x32x16_bf16(al0, wh[i], acc0, 0, 0, 0);
        acc1 = __builtin_amdgcn_mfma_f32_32x32x16_bf16(ah1, wh[i], acc1, 0, 0, 0);
        acc1 = __builtin_amdgcn_mfma_f32_32x32x16_bf16(ah1, wl[i], acc1, 0, 0, 0);
        acc1 = __builtin_amdgcn_mfma_f32_32x32x16_bf16(al1, wh[i], acc1, 0, 0, 0);
      }

      // deposit K-half partials (lane-stride-1: conflict-free)
#pragma unroll
      for (int r = 0; r < 16; ++r) {
        int row = (r & 3) + 8 * (r >> 2) + 4 * lh;
        comb[kqh][nt][row][l31] = acc0[r];
        comb[kqh][nt][row + 32][l31] = acc1[r];
      }
      __syncthreads();

      // epilogue: 512 threads x 4 cells over the 64x32 tile
      int col = tid & 31;
      int rowb = (tid >> 5) * 4;
#pragma unroll
      for (int j = 0; j < 4; ++j) {
        int row = rowb + j;
        float g[4];
#pragma unroll
        for (int q = 0; q < 4; ++q)
          g[q] = (comb[0][q][row][col] + comb[1][q][row][col]) + bias[q];
        float cp = creg[j];
        float cn = sigf(g[1]) * cp + sigf(g[0]) * tanhfast(g[2]);
        float hn = sigf(g[3]) * tanhfast(cn);
        creg[j] = cn;
        int brow = b0 + row;
        int hcol = ng * 32 + col;
        size_t o = ((((size_t)layer * 2 + (step & 1)) * 32 + (hcol >> 4)) * H + brow) * 16 +
                   (hcol & 15);
        unsigned ub = __float_as_uint(hn);
        hFhi[o] = (short)(ub >> 16);
        hFlo[o] = (short)bf16_rne(hn - __uint_as_float(ub & 0xffff0000u));
        if (layer) planes[(size_t)step * BH + (size_t)brow * H + hcol] = hn;  // hsq
      }
    }

    // ---- grid barrier + release/acquire coherence (96x) ----
    if (tt < T) {
      __syncthreads();  // all block stores drained to L2 (per-wave vmcnt(0))
      if (tid == 0) {
        __threadfence_system();  // release: buffer_wbl2 -> lines to IF$
        __hip_atomic_fetch_add(bar, 1u, __ATOMIC_RELAXED, __HIP_MEMORY_SCOPE_SYSTEM);
        unsigned tgt = 256u * (unsigned)(tt + 1);
        while (__hip_atomic_load(bar, __ATOMIC_RELAXED, __HIP_MEMORY_SCOPE_SYSTEM) < tgt)
          __builtin_amdgcn_s_sleep(2);
        __threadfence_system();  // acquire: buffer_inv -> L1/L2 invalidated
      }
      __syncthreads();
    }
  }
}

// ---- Kernel 4: conv, hs planes are [t][b][h] ----
__global__ __launch_bounds__(256) void k_conv(
    const float* __restrict__ hs, const float* __restrict__ cW,
    const float* __restrict__ cb, float* __restrict__ feat) {
  int b = blockIdx.x >> 2;
  int h0 = (blockIdx.x & 3) * 128;
  int tid = threadIdx.x;
  __shared__ float sW[TM1][FN];
  for (int i = tid; i < TM1 * FN; i += 256) sW[i >> 5][i & 31] = cW[(i & 31) * TM1 + (i >> 5)];
  __syncthreads();
  int hl = tid & 127, fg = (tid >> 7) * 16;
  float acc[16];
#pragma unroll
  for (int j = 0; j < 16; ++j) acc[j] = cb[fg + j];
  const float* hp = hs + (size_t)b * H + h0 + hl;
  for (int t = 0; t < TM1; ++t) {
    float v = fmaxf(hp[(size_t)t * BH], 0.f);
#pragma unroll
    for (int j = 0; j < 16; ++j) acc[j] = fmaf(v, sW[t][fg + j], acc[j]);
  }
#pragma unroll
  for (int j = 0; j < 16; ++j)
    feat[(size_t)b * (FN * H) + (size_t)(fg + j) * H + h0 + hl] = fmaxf(acc[j], 0.f);
}

// ---- Kernel 5: attention + head; htt = plane T-1 ----
__global__ __launch_bounds__(256) void k_attn(
    const float* __restrict__ hs, const float* __restrict__ feat,
    const float* __restrict__ W1, const float* __restrict__ b1,
    const float* __restrict__ W2, const float* __restrict__ b2,
    const float* __restrict__ Wout, const float* __restrict__ bout,
    float* __restrict__ out) {
  int b = blockIdx.x, tid = threadIdx.x;
  __shared__ float sh[H], sa[H], snew[H], sw[FN], sv[FN], red[256];
  const float* htt = hs + (size_t)(T - 1) * BH + (size_t)b * H;
  for (int i = tid; i < H; i += 256) sh[i] = htt[i];
  __syncthreads();
  {
    int f = tid >> 3, sl = tid & 7;
    const float* w1 = W1 + (size_t)f * H;
    float p = 0.f;
    for (int k = sl * 64; k < sl * 64 + 64; ++k) p = fmaf(sh[k], w1[k], p);
    p += __shfl_xor(p, 1); p += __shfl_xor(p, 2); p += __shfl_xor(p, 4);
    if (sl == 0) sw[f] = p + b1[f];
  }
  __syncthreads();
  const float* fb = feat + (size_t)b * (FN * H);
  for (int i = tid; i < H; i += 256) {
    const float* fr = fb + (size_t)i * FN;
    float p = 0.f;
#pragma unroll
    for (int j = 0; j < FN; j += 4) {
      float4 fv = *(const float4*)(fr + j);
      p = fmaf(fv.x, sw[j], p);
      p = fmaf(fv.y, sw[j + 1], p);
      p = fmaf(fv.z, sw[j + 2], p);
      p = fmaf(fv.w, sw[j + 3], p);
    }
    sa[i] = sigf(p);
  }
  __syncthreads();
  {
    int j = tid & 31, isl = tid >> 5;
    float p = 0.f;
    for (int i = isl * 64; i < isl * 64 + 64; ++i) p = fmaf(sa[i], fb[(size_t)i * FN + j], p);
    red[tid] = p;
  }
  __syncthreads();
  if (tid < 128) red[tid] += red[tid + 128];
  __syncthreads();
  if (tid < 64) red[tid] += red[tid + 64];
  __syncthreads();
  if (tid < 32) sv[tid] = red[tid] + red[tid + 32];
  __syncthreads();
  for (int h = tid; h < H; h += 256) {
    const float* w2 = W2 + (size_t)h * KC;
    float p = b2[h];
#pragma unroll 4
    for (int k = 0; k < H; k += 4) {
      float4 wv = *(const float4*)(w2 + k);
      float4 shv = *(const float4*)(sh + k);
      p = fmaf(shv.x, wv.x, p);
      p = fmaf(shv.y, wv.y, p);
      p = fmaf(shv.z, wv.z, p);
      p = fmaf(shv.w, wv.w, p);
    }
#pragma unroll
    for (int j = 0; j < FN; j += 4) {
      float4 wv = *(const float4*)(w2 + H + j);
      p = fmaf(sv[j], wv.x, p);
      p = fmaf(sv[j + 1], wv.y, p);
      p = fmaf(sv[j + 2], wv.z, p);
      p = fmaf(sv[j + 3], wv.w, p);
    }
    snew[h] = p;
  }
  __syncthreads();
  if (tid < NPRED * 8) {
    int p = tid >> 3, sl = tid & 7;
    const float* wo = Wout + (size_t)(T - NPRED + p) * H;
    float sacc = 0.f;
    for (int k = sl * 64; k < sl * 64 + 64; ++k) sacc = fmaf(snew[k], wo[k], sacc);
    sacc += __shfl_xor(sacc, 1); sacc += __shfl_xor(sacc, 2); sacc += __shfl_xor(sacc, 4);
    if (sl == 0) out[(size_t)b * NPRED + p] = sacc + bout[T - NPRED + p];
  }
}

}  // namespace

extern "C" void kernel_launch(void* const* d_in, const int* in_sizes, int n_in,
                              void* d_out, int out_size, void* d_ws, size_t ws_size,
                              hipStream_t stream) {
  const float* x    = (const float*)d_in[0];
  const int*   sid  = (const int*)d_in[1];
  const float* Wh   = (const float*)d_in[2];
  const float* bh   = (const float*)d_in[3];
  const float* emb  = (const float*)d_in[4];
  const float* Wih  = (const float*)d_in[5];
  const float* Whh  = (const float*)d_in[6];
  const float* bih  = (const float*)d_in[7];
  const float* bhh  = (const float*)d_in[8];
  const float* cW   = (const float*)d_in[9];
  const float* cb   = (const float*)d_in[10];
  const float* W1   = (const float*)d_in[11];
  const float* b1   = (const float*)d_in[12];
  const float* W2   = (const float*)d_in[13];
  const float* b2   = (const float*)d_in[14];
  const float* Wout = (const float*)d_in[15];
  const float* bout = (const float*)d_in[16];
  float* out = (float*)d_out;

  // ws: planes (xc, hsq in place) | WF hi/lo | hF hi/lo | bar | feat
  constexpr size_t HFE = (size_t)2 * 2 * 32 * H * 16;  // shorts per hF array
  float* planes = (float*)d_ws;
  short* WFhi = (short*)(planes + (size_t)T * BH);
  short* WFlo = WFhi + (size_t)8192 * 512;
  short* hFhi = WFlo + (size_t)8192 * 512;
  short* hFlo = hFhi + HFE;
  unsigned* bar = (unsigned*)(hFlo + HFE);
  float* feat = (float*)(bar + 1024);
  size_t need = (size_t)T * BH * 4 + (size_t)8192 * 512 * 2 * 2 + HFE * 2 * 2 + 4096 +
                (size_t)B * FN * H * 4;
  if (ws_size < need) return;

  // zero initial h states + barrier counter (contiguous; re-zeroed per replay)
  hipMemsetAsync(hFhi, 0, HFE * 2 * 2 + 4096, stream);
  k_xc<<<(B * T / 64) * 2, 256, 0, stream>>>(x, sid, Wh, bh, emb, planes);
  k_wswz<<<2048, 256, 0, stream>>>(Wih, Whh, WFhi, WFlo);

  k_lstm6<<<256, 512, 0, stream>>>(planes, WFhi, WFlo, hFhi, hFlo, bih, bhh, bar);

  k_conv<<<B * 4, 256, 0, stream>>>(planes, cW, cb, feat);
  k_attn<<<B, 256, 0, stream>>>(planes, feat, W1, b1, W2, b2, Wout, bout, out);
}

// Round 7
// 2254.046 us; speedup vs baseline: 2.2886x; 2.2886x over previous
//
#include <hip/hip_runtime.h>
#include <math.h>

namespace {

constexpr int B = 512, T = 96, IN = 64, H = 512, G4 = 2048;
constexpr int FN = 32, KC = 544, NPRED = 24, TM1 = T - 1;
constexpr int BH = B * H;

typedef __attribute__((ext_vector_type(8))) short s8v;    // 8 bf16
typedef __attribute__((ext_vector_type(16))) float f16v;  // 32x32 acc

__device__ __forceinline__ float sigf(float x) { return 1.0f / (1.0f + __expf(-x)); }
__device__ __forceinline__ float tanhfast(float x) {
  x = fminf(fmaxf(x, -15.f), 15.f);
  float e = __expf(2.0f * x);
  return (e - 1.0f) / (e + 1.0f);
}
__device__ __forceinline__ unsigned short bf16_rne(float f) {
  unsigned u = __float_as_uint(f);
  u += 0x7fffu + ((u >> 16) & 1u);
  return (unsigned short)(u >> 16);
}
__device__ __forceinline__ void split8(const float4& x, const float4& y, s8v& hi, s8v& lo) {
  float vs[8] = {x.x, x.y, x.z, x.w, y.x, y.y, y.z, y.w};
#pragma unroll
  for (int j = 0; j < 8; ++j) {
    unsigned ub = __float_as_uint(vs[j]);
    hi[j] = (short)(ub >> 16);
    lo[j] = (short)bf16_rne(vs[j] - __uint_as_float(ub & 0xffff0000u));
  }
}

// ---- Kernel 1: xc = relu(x @ Wh^T + bh) + embed[sid], f32 planes [t][b][h] ----
// v4: LDS-port diagnosis (r6): 1024 ds_read_b128/thread x 12cy was the floor.
// Two h's per thread (w regs x2 = 128 VGPR): same LDS reads feed 2x FMAs.
__global__ __launch_bounds__(256) void k_xc(
    const float* __restrict__ x, const int* __restrict__ sid,
    const float* __restrict__ Wh, const float* __restrict__ bh,
    const float* __restrict__ emb, float* __restrict__ planes) {
  constexpr int RWS = 64;
  int row0 = blockIdx.x * RWS;
  int tid = threadIdx.x;
  __shared__ __align__(16) float sx[RWS][IN];  // 16 KB
  {
    const float4* xsrc = (const float4*)(x + (size_t)row0 * IN);
    float4* sdst = (float4*)(&sx[0][0]);
    for (int i = tid; i < RWS * IN / 4; i += 256) sdst[i] = xsrc[i];
  }
  float4 w0[16], w1[16];
  const float* wr0 = Wh + (size_t)tid * IN;
  const float* wr1 = Wh + (size_t)(tid + 256) * IN;
#pragma unroll
  for (int j = 0; j < 16; ++j) {
    w0[j] = *(const float4*)(wr0 + j * 4);
    w1[j] = *(const float4*)(wr1 + j * 4);
  }
  float bb0 = bh[tid], bb1 = bh[tid + 256];
  __syncthreads();
#pragma unroll 2
  for (int r = 0; r < RWS; ++r) {
    float a00 = bb0, a01 = 0.f, a02 = 0.f, a03 = 0.f;
    float a10 = bb1, a11 = 0.f, a12 = 0.f, a13 = 0.f;
#pragma unroll
    for (int j = 0; j < 16; ++j) {
      float4 xv = *(const float4*)(&sx[r][j * 4]);
      a00 = fmaf(xv.x, w0[j].x, a00);
      a01 = fmaf(xv.y, w0[j].y, a01);
      a02 = fmaf(xv.z, w0[j].z, a02);
      a03 = fmaf(xv.w, w0[j].w, a03);
      a10 = fmaf(xv.x, w1[j].x, a10);
      a11 = fmaf(xv.y, w1[j].y, a11);
      a12 = fmaf(xv.z, w1[j].z, a12);
      a13 = fmaf(xv.w, w1[j].w, a13);
    }
    float acc0 = (a00 + a01) + (a02 + a03);
    float acc1 = (a10 + a11) + (a12 + a13);
    int row = row0 + r;
    int bb = row / T, t = row % T;
    const float* eb = emb + (size_t)sid[bb] * H;
    size_t o = ((size_t)t * B + bb) * H;
    planes[o + tid] = fmaxf(acc0, 0.f) + eb[tid];
    planes[o + tid + 256] = fmaxf(acc1, 0.f) + eb[tid + 256];
  }
}

// ---- Kernel 2: pre-swizzle weights into frag-linear split-bf16 ----
// frag f = ((layer*16+ng)*64 + kt)*4 + nt ; element o = f*512 + lane*8
// frag content: n-row = nt*512 + ng*32 + (lane&31); k = kt*16 + (lane>>5)*8 + j
__global__ __launch_bounds__(256) void k_wswz(
    const float* __restrict__ Wih, const float* __restrict__ Whh,
    short* __restrict__ WFhi, short* __restrict__ WFlo) {
  int g = blockIdx.x * 256 + threadIdx.x;
  int lane = g & 63;
  int fi = g >> 6;  // 0..8191
  int nt = fi & 3, kt = (fi >> 2) & 63, ng = (fi >> 8) & 15, layer = fi >> 12;
  int row = nt * H + ng * 32 + (lane & 31);
  int kk = kt * 16 + (lane >> 5) * 8;
  const float* src = (kk < H) ? (Wih + ((size_t)layer * G4 + row) * H + kk)
                              : (Whh + ((size_t)layer * G4 + row) * H + (kk - H));
  float4 f0 = *(const float4*)src, f1 = *(const float4*)(src + 4);
  s8v hi, lo;
  split8(f0, f1, hi, lo);
  size_t o = (size_t)fi * 512 + lane * 8;
  *(s8v*)(WFhi + o) = hi;
  *(s8v*)(WFlo + o) = lo;
}

// ---- Kernel 2c: transpose W2 into [k/4][h][4] for coalesced GEMV ----
__global__ __launch_bounds__(256) void k_w2t(
    const float* __restrict__ W2, float* __restrict__ W2T4) {
  int g = blockIdx.x * 256 + threadIdx.x;  // over H*KC = 278528
  int h = g / KC, k = g % KC;
  W2T4[((size_t)(k >> 2) * H + h) * 4 + (k & 3)] = W2[g];
}

// ---- Kernel 3: dual-layer staggered LSTM step (round-2 proven, 21us/step) ----
// RT=2: 256 blocks x 256 thr (1/CU), each block 64 b-rows x 32 h-cols x 4
// gates. 3-deep statically-named reg pipeline; kernel-boundary coherence.
__global__ __launch_bounds__(256, 1) void k_step(
    int tt, float* __restrict__ planes, const short* __restrict__ WFhi,
    const short* __restrict__ WFlo, short* __restrict__ hFhi,
    short* __restrict__ hFlo, const float* __restrict__ bih,
    const float* __restrict__ bhh, float* __restrict__ c0,
    float* __restrict__ c1) {
  int gid = blockIdx.x;
  int xcd = gid & 7;
  int u = gid >> 3;              // 0..31
  int combo = xcd * 4 + (u & 3); // 0..31
  int layer = combo >> 4;
  if (layer ? (tt == 0) : (tt == T)) return;
  int ng = combo & 15;
  int b0 = (u >> 2) * 64;        // btile 0..7, 64 rows each
  int step = layer ? (tt - 1) : tt;
  int tid = threadIdx.x, lane = tid & 63, wk = tid >> 6;
  int l31 = lane & 31, lh = lane >> 5;

  __shared__ float comb[4][4][32][32];  // [nt][wk][row][col] 64 KB, 2 passes

  const float* bi = bih + (size_t)layer * G4;
  const float* bh2 = bhh + (size_t)layer * G4;
  float* cbuf = layer ? c1 : c0;

  int rpar = (step - 1) & 1;  // (-1)&1 == 1: initial zero-state buffer
  const float* xbase = nullptr;
  const short *abhi = nullptr, *ablo = nullptr;
  if (layer == 0 && wk < 2) {
    xbase = planes + (size_t)step * BH + (size_t)(b0 + l31) * H + wk * 256 + lh * 8;
  } else {
    int src = (layer == 0) ? 0 : ((wk < 2) ? 0 : 1);
    int par = (layer == 0) ? rpar : ((wk < 2) ? (step & 1) : rpar);
    int kk0 = wk * 16 - ((layer == 0 || wk >= 2) ? 32 : 0);
    size_t o = ((((size_t)src * 2 + par) * 32 + kk0) * H + (b0 + l31)) * 16 + lh * 8;
    abhi = hFhi + o;
    ablo = hFlo + o;
  }

  float bias[4];
#pragma unroll
  for (int nt = 0; nt < 4; ++nt) {
    int r = nt * H + ng * 32 + l31;
    bias[nt] = bi[r] + bh2[r];
  }

  const size_t wstep = 4 * 512;  // shorts per kt
  const size_t wbase0 = ((size_t)(layer * 16 + ng) * 64 + wk * 16) * wstep + (size_t)lane * 8;
  const size_t astep = (size_t)H * 16;  // shorts per kt in hF; rt1 = +512

  f16v acc[2][4];
#pragma unroll
  for (int rt = 0; rt < 2; ++rt)
#pragma unroll
    for (int nt = 0; nt < 4; ++nt)
#pragma unroll
      for (int e = 0; e < 16; ++e) acc[rt][nt][e] = 0.f;

  // statically-named 3-deep pipelined operand sets (rule #20), 2 row-tiles
  s8v a0h0, a0l0, a0h1, a0l1, b0h0, b0h1, b0h2, b0h3, b0l0, b0l1, b0l2, b0l3;
  s8v a1h0, a1l0, a1h1, a1l1, b1h0, b1h1, b1h2, b1h3, b1l0, b1l1, b1l2, b1l3;
  s8v a2h0, a2l0, a2h1, a2l1, b2h0, b2h1, b2h2, b2h3, b2l0, b2l1, b2l2, b2l3;

#define LOADW_(kq, bh0, bh1, bh2, bh3, bl0, bl1, bl2, bl3)          \
  {                                                                 \
    size_t wo = wbase0 + (size_t)(kq) * wstep;                      \
    bh0 = *(const s8v*)(WFhi + wo);                                 \
    bh1 = *(const s8v*)(WFhi + wo + 512);                           \
    bh2 = *(const s8v*)(WFhi + wo + 1024);                          \
    bh3 = *(const s8v*)(WFhi + wo + 1536);                          \
    bl0 = *(const s8v*)(WFlo + wo);                                 \
    bl1 = *(const s8v*)(WFlo + wo + 512);                           \
    bl2 = *(const s8v*)(WFlo + wo + 1024);                          \
    bl3 = *(const s8v*)(WFlo + wo + 1536);                          \
  }
#define LOADA_(kq, ah0, al0, ah1, al1)                              \
  {                                                                 \
    if (xbase) {                                                    \
      const float* ap = xbase + (kq) * 16;                          \
      float4 f0 = *(const float4*)ap, f1 = *(const float4*)(ap + 4);\
      split8(f0, f1, ah0, al0);                                     \
      const float* aq = ap + 32 * H;                                \
      float4 g0 = *(const float4*)aq, g1 = *(const float4*)(aq + 4);\
      split8(g0, g1, ah1, al1);                                     \
    } else {                                                        \
      const short* ph_ = abhi + (size_t)(kq) * astep;               \
      const short* pl_ = ablo + (size_t)(kq) * astep;               \
      ah0 = *(const s8v*)(ph_);                                     \
      al0 = *(const s8v*)(pl_);                                     \
      ah1 = *(const s8v*)(ph_ + 512);                               \
      al1 = *(const s8v*)(pl_ + 512);                               \
    }                                                               \
  }
#define MFMA3R_(rt, ah, al, bh0, bh1, bh2, bh3, bl0, bl1, bl2, bl3)                        \
  {                                                                                        \
    acc[rt][0] = __builtin_amdgcn_mfma_f32_32x32x16_bf16(ah, bh0, acc[rt][0], 0, 0, 0);    \
    acc[rt][1] = __builtin_amdgcn_mfma_f32_32x32x16_bf16(ah, bh1, acc[rt][1], 0, 0, 0);    \
    acc[rt][2] = __builtin_amdgcn_mfma_f32_32x32x16_bf16(ah, bh2, acc[rt][2], 0, 0, 0);    \
    acc[rt][3] = __builtin_amdgcn_mfma_f32_32x32x16_bf16(ah, bh3, acc[rt][3], 0, 0, 0);    \
    acc[rt][0] = __builtin_amdgcn_mfma_f32_32x32x16_bf16(ah, bl0, acc[rt][0], 0, 0, 0);    \
    acc[rt][1] = __builtin_amdgcn_mfma_f32_32x32x16_bf16(ah, bl1, acc[rt][1], 0, 0, 0);    \
    acc[rt][2] = __builtin_amdgcn_mfma_f32_32x32x16_bf16(ah, bl2, acc[rt][2], 0, 0, 0);    \
    acc[rt][3] = __builtin_amdgcn_mfma_f32_32x32x16_bf16(ah, bl3, acc[rt][3], 0, 0, 0);    \
    acc[rt][0] = __builtin_amdgcn_mfma_f32_32x32x16_bf16(al, bh0, acc[rt][0], 0, 0, 0);    \
    acc[rt][1] = __builtin_amdgcn_mfma_f32_32x32x16_bf16(al, bh1, acc[rt][1], 0, 0, 0);    \
    acc[rt][2] = __builtin_amdgcn_mfma_f32_32x32x16_bf16(al, bh2, acc[rt][2], 0, 0, 0);    \
    acc[rt][3] = __builtin_amdgcn_mfma_f32_32x32x16_bf16(al, bh3, acc[rt][3], 0, 0, 0);    \
  }
#define MFMA6_(ah0, al0, ah1, al1, bh0, bh1, bh2, bh3, bl0, bl1, bl2, bl3)  \
  {                                                                         \
    MFMA3R_(0, ah0, al0, bh0, bh1, bh2, bh3, bl0, bl1, bl2, bl3);           \
    MFMA3R_(1, ah1, al1, bh0, bh1, bh2, bh3, bl0, bl1, bl2, bl3);           \
  }

  LOADA_(0, a0h0, a0l0, a0h1, a0l1);
  LOADW_(0, b0h0, b0h1, b0h2, b0h3, b0l0, b0l1, b0l2, b0l3);
  LOADA_(1, a1h0, a1l0, a1h1, a1l1);
  LOADW_(1, b1h0, b1h1, b1h2, b1h3, b1l0, b1l1, b1l2, b1l3);
  LOADA_(2, a2h0, a2l0, a2h1, a2l1);
  LOADW_(2, b2h0, b2h1, b2h2, b2h3, b2l0, b2l1, b2l2, b2l3);
#pragma unroll 1
  for (int kp = 0; kp < 5; ++kp) {
    int kq = kp * 3;
    MFMA6_(a0h0, a0l0, a0h1, a0l1, b0h0, b0h1, b0h2, b0h3, b0l0, b0l1, b0l2, b0l3);
    LOADA_(kq + 3, a0h0, a0l0, a0h1, a0l1);  // kq+3 <= 15 always
    LOADW_(kq + 3, b0h0, b0h1, b0h2, b0h3, b0l0, b0l1, b0l2, b0l3);
    MFMA6_(a1h0, a1l0, a1h1, a1l1, b1h0, b1h1, b1h2, b1h3, b1l0, b1l1, b1l2, b1l3);
    if (kp < 4) {
      LOADA_(kq + 4, a1h0, a1l0, a1h1, a1l1);
      LOADW_(kq + 4, b1h0, b1h1, b1h2, b1h3, b1l0, b1l1, b1l2, b1l3);
    }
    MFMA6_(a2h0, a2l0, a2h1, a2l1, b2h0, b2h1, b2h2, b2h3, b2l0, b2l1, b2l2, b2l3);
    if (kp < 4) {
      LOADA_(kq + 5, a2h0, a2l0, a2h1, a2l1);
      LOADW_(kq + 5, b2h0, b2h1, b2h2, b2h3, b2l0, b2l1, b2l2, b2l3);
    }
  }
  MFMA6_(a0h0, a0l0, a0h1, a0l1, b0h0, b0h1, b0h2, b0h3, b0l0, b0l1, b0l2, b0l3);  // kq=15
#undef LOADW_
#undef LOADA_
#undef MFMA3R_
#undef MFMA6_

  // two passes over row-tiles; comb reused (64 KB)
#pragma unroll
  for (int rt = 0; rt < 2; ++rt) {
    if (rt) __syncthreads();  // rt0 epilogue readers done before overwrite
#pragma unroll
    for (int nt = 0; nt < 4; ++nt)
#pragma unroll
      for (int r = 0; r < 16; ++r) {
        int row = (r & 3) + 8 * (r >> 2) + 4 * lh;
        comb[nt][wk][row][l31] = acc[rt][nt][r];
      }
    __syncthreads();
    int b0p = b0 + rt * 32;
#pragma unroll
    for (int rr = 0; rr < 4; ++rr) {
      int r = wk * 4 + rr;
      int row = (r & 3) + 8 * (r >> 2) + 4 * lh;
      float g[4];
#pragma unroll
      for (int nt = 0; nt < 4; ++nt) {
        float p0 = comb[nt][0][row][l31];
        float p1 = comb[nt][1][row][l31];
        float p2 = comb[nt][2][row][l31];
        float p3 = comb[nt][3][row][l31];
        g[nt] = (p0 + p1) + (p2 + p3) + bias[nt];
      }
      size_t coff = (size_t)(b0p + row) * H + ng * 32 + l31;
      float cp = cbuf[coff];
      float cn = sigf(g[1]) * cp + sigf(g[0]) * tanhfast(g[2]);
      float hn = sigf(g[3]) * tanhfast(cn);
      cbuf[coff] = cn;
      int brow = b0p + row;
      int hcol = ng * 32 + l31;
      size_t o = ((((size_t)layer * 2 + (step & 1)) * 32 + (hcol >> 4)) * H + brow) * 16 + (hcol & 15);
      unsigned ub = __float_as_uint(hn);
      hFhi[o] = (short)(ub >> 16);
      hFlo[o] = (short)bf16_rne(hn - __uint_as_float(ub & 0xffff0000u));
      if (layer) planes[(size_t)step * BH + (size_t)brow * H + hcol] = hn;  // hsq
    }
  }
}

// ---- Kernel 4: conv, hs planes are [t][b][h] ----
__global__ __launch_bounds__(256) void k_conv(
    const float* __restrict__ hs, const float* __restrict__ cW,
    const float* __restrict__ cb, float* __restrict__ feat) {
  int b = blockIdx.x >> 2;
  int h0 = (blockIdx.x & 3) * 128;
  int tid = threadIdx.x;
  __shared__ float sW[TM1][FN];
  for (int i = tid; i < TM1 * FN; i += 256) sW[i >> 5][i & 31] = cW[(i & 31) * TM1 + (i >> 5)];
  __syncthreads();
  int hl = tid & 127, fg = (tid >> 7) * 16;
  float acc[16];
#pragma unroll
  for (int j = 0; j < 16; ++j) acc[j] = cb[fg + j];
  const float* hp = hs + (size_t)b * H + h0 + hl;
  for (int t = 0; t < TM1; ++t) {
    float v = fmaxf(hp[(size_t)t * BH], 0.f);
#pragma unroll
    for (int j = 0; j < 16; ++j) acc[j] = fmaf(v, sW[t][fg + j], acc[j]);
  }
#pragma unroll
  for (int j = 0; j < 16; ++j)
    feat[(size_t)b * (FN * H) + (size_t)(fg + j) * H + h0 + hl] = fmaxf(acc[j], 0.f);
}

// ---- Kernel 5 (v2): attention + head, fully coalesced ----
// Old version: 92us, 1.6M LDS bank conflicts, lane-stride-128B feat gathers
// (2 passes) + lane-stride-2176B W2 gathers. New: fused alpha+v single
// coalesced feat pass (8 lanes/row + shfl; feat read ONCE), W2 pre-transposed
// to [k/4][h][4] so GEMV loads are lane-coalesced float4.
__global__ __launch_bounds__(256) void k_attn(
    const float* __restrict__ hs, const float* __restrict__ feat,
    const float* __restrict__ W1, const float* __restrict__ b1,
    const float* __restrict__ W2T4, const float* __restrict__ b2,
    const float* __restrict__ Wout, const float* __restrict__ bout,
    float* __restrict__ out) {
  int b = blockIdx.x, tid = threadIdx.x;
  __shared__ __align__(16) float sh[H], snew[H], sw[FN], sv[FN];
  __shared__ __align__(16) float4 red4[32][8];  // 4 KB
  const float* htt = hs + (size_t)(T - 1) * BH + (size_t)b * H;
  for (int i = tid; i < H; i += 256) sh[i] = htt[i];
  __syncthreads();
  {
    int f = tid >> 3, sl = tid & 7;
    const float* w1 = W1 + (size_t)f * H;
    float p = 0.f;
    for (int k = sl * 64; k < sl * 64 + 64; ++k) p = fmaf(sh[k], w1[k], p);
    p += __shfl_xor(p, 1); p += __shfl_xor(p, 2); p += __shfl_xor(p, 4);
    if (sl == 0) sw[f] = p + b1[f];
  }
  __syncthreads();
  // fused alpha+v: flat feat view, wave covers 8 rows x 128B contiguous
  const float* fb = feat + (size_t)b * (FN * H);
  int ig = tid >> 3, j0 = (tid & 7) * 4;
  float4 swv = *(const float4*)(&sw[j0]);
  float4 vacc = {0.f, 0.f, 0.f, 0.f};
#pragma unroll 4
  for (int p = 0; p < 16; ++p) {
    int i = p * 32 + ig;
    float4 f4 = *(const float4*)(fb + (size_t)i * FN + j0);
    float s = f4.x * swv.x;
    s = fmaf(f4.y, swv.y, s);
    s = fmaf(f4.z, swv.z, s);
    s = fmaf(f4.w, swv.w, s);
    s += __shfl_xor(s, 1); s += __shfl_xor(s, 2); s += __shfl_xor(s, 4);
    s = sigf(s);  // all 8 lanes hold alpha[i]
    vacc.x = fmaf(s, f4.x, vacc.x);
    vacc.y = fmaf(s, f4.y, vacc.y);
    vacc.z = fmaf(s, f4.z, vacc.z);
    vacc.w = fmaf(s, f4.w, vacc.w);
  }
  red4[ig][tid & 7] = vacc;
  __syncthreads();
#pragma unroll
  for (int s2 = 16; s2 >= 1; s2 >>= 1) {
    if (tid < s2 * 8) {
      float4 a = red4[tid >> 3][tid & 7];
      float4 c = red4[(tid >> 3) + s2][tid & 7];
      a.x += c.x; a.y += c.y; a.z += c.z; a.w += c.w;
      red4[tid >> 3][tid & 7] = a;
    }
    __syncthreads();
  }
  if (tid < FN) sv[tid] = ((const float*)&red4[0][0])[tid];
  __syncthreads();
  // snew = W2 @ [sh; sv] + b2, coalesced via W2T4 [k/4][h][4]
#pragma unroll
  for (int q = 0; q < 2; ++q) {
    int h = tid + q * 256;
    float p = b2[h];
    const float* wt = W2T4 + (size_t)h * 4;
#pragma unroll 4
    for (int kg = 0; kg < 128; ++kg) {
      float4 wv = *(const float4*)(wt + (size_t)kg * (H * 4));
      float4 shv = *(const float4*)(&sh[kg * 4]);
      p = fmaf(shv.x, wv.x, p);
      p = fmaf(shv.y, wv.y, p);
      p = fmaf(shv.z, wv.z, p);
      p = fmaf(shv.w, wv.w, p);
    }
#pragma unroll
    for (int kg = 128; kg < 136; ++kg) {
      float4 wv = *(const float4*)(wt + (size_t)kg * (H * 4));
      float4 svv = *(const float4*)(&sv[(kg - 128) * 4]);
      p = fmaf(svv.x, wv.x, p);
      p = fmaf(svv.y, wv.y, p);
      p = fmaf(svv.z, wv.z, p);
      p = fmaf(svv.w, wv.w, p);
    }
    snew[h] = p;
  }
  __syncthreads();
  if (tid < NPRED * 8) {
    int p = tid >> 3, sl = tid & 7;
    const float* wo = Wout + (size_t)(T - NPRED + p) * H;
    float sacc = 0.f;
    for (int k = sl * 64; k < sl * 64 + 64; ++k) sacc = fmaf(snew[k], wo[k], sacc);
    sacc += __shfl_xor(sacc, 1); sacc += __shfl_xor(sacc, 2); sacc += __shfl_xor(sacc, 4);
    if (sl == 0) out[(size_t)b * NPRED + p] = sacc + bout[T - NPRED + p];
  }
}

}  // namespace

extern "C" void kernel_launch(void* const* d_in, const int* in_sizes, int n_in,
                              void* d_out, int out_size, void* d_ws, size_t ws_size,
                              hipStream_t stream) {
  const float* x    = (const float*)d_in[0];
  const int*   sid  = (const int*)d_in[1];
  const float* Wh   = (const float*)d_in[2];
  const float* bh   = (const float*)d_in[3];
  const float* emb  = (const float*)d_in[4];
  const float* Wih  = (const float*)d_in[5];
  const float* Whh  = (const float*)d_in[6];
  const float* bih  = (const float*)d_in[7];
  const float* bhh  = (const float*)d_in[8];
  const float* cW   = (const float*)d_in[9];
  const float* cb   = (const float*)d_in[10];
  const float* W1   = (const float*)d_in[11];
  const float* b1   = (const float*)d_in[12];
  const float* W2   = (const float*)d_in[13];
  const float* b2   = (const float*)d_in[14];
  const float* Wout = (const float*)d_in[15];
  const float* bout = (const float*)d_in[16];
  float* out = (float*)d_out;

  // ws: planes (xc, hsq in place) | WF hi/lo | hF hi/lo | c0,c1 | feat | W2T4
  constexpr size_t HFE = (size_t)2 * 2 * 32 * H * 16;  // shorts per hF array
  float* planes = (float*)d_ws;
  short* WFhi = (short*)(planes + (size_t)T * BH);
  short* WFlo = WFhi + (size_t)8192 * 512;
  short* hFhi = WFlo + (size_t)8192 * 512;
  short* hFlo = hFhi + HFE;
  float* cst = (float*)(hFlo + HFE);
  float* c0 = cst;
  float* c1 = cst + BH;
  float* feat = c1 + BH;
  float* w2t4 = feat + (size_t)B * FN * H;
  size_t need = (size_t)T * BH * 4 + (size_t)8192 * 512 * 2 * 2 + HFE * 2 * 2 +
                2 * (size_t)BH * 4 + (size_t)B * FN * H * 4 + (size_t)KC * H * 4;
  if (ws_size < need) return;

  // zero initial h states + c states (contiguous region)
  hipMemsetAsync(hFhi, 0, HFE * 2 * 2 + 2 * (size_t)BH * 4, stream);
  k_xc<<<B * T / 64, 256, 0, stream>>>(x, sid, Wh, bh, emb, planes);
  k_wswz<<<2048, 256, 0, stream>>>(Wih, Whh, WFhi, WFlo);
  k_w2t<<<(H * KC) / 256, 256, 0, stream>>>(W2, w2t4);

  for (int tt = 0; tt <= T; ++tt)
    k_step<<<256, 256, 0, stream>>>(tt, planes, WFhi, WFlo, hFhi, hFlo, bih, bhh, c0, c1);

  k_conv<<<B * 4, 256, 0, stream>>>(planes, cW, cb, feat);
  k_attn<<<B, 256, 0, stream>>>(planes, feat, W1, b1, w2t4, b2, Wout, bout, out);
}